// Round 3
// baseline (1105.062 us; speedup 1.0000x reference)
//
#include <hip/hip_runtime.h>
#include <hip/hip_bf16.h>
#include <hip/hip_cooperative_groups.h>

namespace cg = cooperative_groups;

typedef unsigned short u16;
typedef __attribute__((ext_vector_type(8))) short s16x8;   // 8 bf16 MFMA A/B frag
typedef __attribute__((ext_vector_type(4))) float f32x4;   // MFMA C/D frag

#define NN 20000
#define HH 64
#define EMBD 300
#define EE 160000
#define BB 4096
#define NODES 40000

// f32 param block offsets (floats) in workspace (after 16-float header)
#define OFF_PROJB 0
#define OFF_MSGB  64
#define OFF_BIH   192
#define OFF_BHH   576
#define OFF_CW1T  960
#define OFF_CB1   3008
#define OFF_CW2   3024
#define OFF_CB2   3040
#define PARAM_SZ  3072

// bf16 frag-swizzled weight blocks (u16 units). Each "frag" = 512 u16 = one
// 16(row)x32(k) B-tile stored so lane L reads its 8 elements at frag*512+L*8.
#define PB_WIH   0        // 2 l x 24 frags (jt 0..11, kt 0..1)
#define PB_WHH   24576
#define PB_WMT   49152    // 2 l x 8 frags (jt 0..3, kt 0..1)
#define PB_PROJT 57344    // 40 frags (frag = jt*10+kt, jt 0..3, kt 0..9)
#define PB_SZ    77824

// projm LDS A-tile row stride (u16): 344 -> 172 dwords, <=2-way bank alias (free)
#define APAD 344

__device__ __forceinline__ float b2f(u16 u) {
    union { unsigned int i; float f; } v; v.i = ((unsigned int)u) << 16; return v.f;
}
__device__ __forceinline__ u16 f2b(float f) {
    union { float f; unsigned int u; } v; v.f = f;
    unsigned int u = v.u;
    return (u16)((u + 0x7FFFu + ((u >> 16) & 1u)) >> 16);   // RNE
}
__device__ __forceinline__ float ldf(const void* p, long long i, int isbf) {
    return isbf ? b2f(((const u16*)p)[i]) : ((const float*)p)[i];
}
__device__ __forceinline__ u16 ldb(const void* p, long long i, int isbf) {
    return isbf ? ((const u16*)p)[i] : f2b(((const float*)p)[i]);
}
__device__ __forceinline__ void stf(void* p, long long i, int isbf, float v) {
    if (isbf) ((u16*)p)[i] = f2b(v);
    else      ((float*)p)[i] = v;
}

// ---------------- dtype sniffer ----------------
__global__ void sniff_kernel(const u16* probe, int* flag)
{
    if (threadIdx.x == 0 && blockIdx.x == 0) {
        int good = 0;
        for (int i = 0; i < 128; i += 2) {
            unsigned int e = (probe[i] >> 7) & 0xFF;
            if (e >= 105 && e <= 127) good++;
        }
        *flag = (good >= 48) ? 1 : 0;
    }
}

// ---------------- param convert + frag swizzle ----------------
__global__ __launch_bounds__(256) void conv_kernel(
    const void* projW, const void* projb, const void* msgW, const void* msgb,
    const void* wih, const void* whh, const void* bih, const void* bhh,
    const void* cw1, const void* cb1, const void* cw2, const void* cb2,
    float* P, u16* PB, const int* flag)
{
    int isbf = *flag;
    int i = blockIdx.x * 256 + threadIdx.x;
    if (i < 64)    P[OFF_PROJB + i] = ldf(projb, i, isbf);
    if (i < 128)   P[OFF_MSGB + i]  = ldf(msgb, i, isbf);
    if (i < 384)   { P[OFF_BIH + i] = ldf(bih, i, isbf); P[OFF_BHH + i] = ldf(bhh, i, isbf); }
    if (i < 2048)  { int t = i >> 7, k = i & 127; P[OFF_CW1T + i] = ldf(cw1, (long long)k * 16 + t, isbf); }
    if (i < 16)    { P[OFF_CB1 + i] = ldf(cb1, i, isbf); P[OFF_CW2 + i] = ldf(cw2, i, isbf); }
    if (i == 0)    P[OFF_CB2] = ldf(cb2, 0, isbf);

    if (i < 24576) {   // Wih/Whh swizzle: per-l 24 frags
        int l = i / 12288, r = i - l * 12288;
        int frag = r >> 9, rr = r & 511, lane = rr >> 3, e = rr & 7;
        int jt = frag >> 1, kt = frag & 1;
        int srow = jt * 16 + (lane & 15);
        int sk = kt * 32 + ((lane >> 4) << 3) + e;
        long long si = (long long)l * 12288 + srow * 64 + sk;
        PB[PB_WIH + i] = ldb(wih, si, isbf);
        PB[PB_WHH + i] = ldb(whh, si, isbf);
    }
    if (i < 8192) {    // msgW^T swizzle
        int l = i >> 12, r = i & 4095;
        int frag = r >> 9, rr = r & 511, lane = rr >> 3, e = rr & 7;
        int jt = frag >> 1, kt = frag & 1;
        int srow = jt * 16 + (lane & 15);
        int sk = kt * 32 + ((lane >> 4) << 3) + e;
        PB[PB_WMT + i] = ldb(msgW, (long long)l * 4096 + sk * 64 + srow, isbf);
    }
    if (i < 20480) {   // projW^T swizzle, k zero-padded >=300
        int frag = i >> 9, rr = i & 511, lane = rr >> 3, e = rr & 7;
        int jt = frag / 10, kt = frag - jt * 10;
        int srow = jt * 16 + (lane & 15);
        int sk = kt * 32 + ((lane >> 4) << 3) + e;
        PB[PB_PROJT + i] = (sk < 300) ? ldb(projW, (long long)sk * 64 + srow, isbf) : (u16)0;
    }
}

// ---------------- CSR build ----------------
__global__ __launch_bounds__(256) void hist_kernel(const int* __restrict__ adj0,
                                                   const int* __restrict__ adj1, int* off)
{
    int e = blockIdx.x * 256 + threadIdx.x;
    if (e >= 2 * EE) return;
    int b = e / EE, le = e - b * EE;
    const int* adj = b ? adj1 : adj0;
    int tgt = adj[2 * le + 1];
    atomicAdd(&off[b * (NN + 1) + tgt + 1], 1);
}

__global__ __launch_bounds__(1024) void scan_kernel(int* off, int* cursor)
{
    int b = blockIdx.x;
    int* o = off + (size_t)b * (NN + 1);
    int* cur = cursor + (size_t)b * NN;
    __shared__ int wsum[16];
    __shared__ int wscan[16];
    int tid = threadIdx.x, wv = tid >> 6, lane = tid & 63;
    int base = 0;
    for (int start = 0; start < NN; start += 1024) {
        int i = start + tid;
        int v = (i < NN) ? o[i + 1] : 0;
        int orig = v;
        #pragma unroll
        for (int d = 1; d < 64; d <<= 1) {
            int t = __shfl_up(v, d);
            if (lane >= d) v += t;
        }
        if (lane == 63) wsum[wv] = v;
        __syncthreads();
        if (tid < 16) {
            int w = wsum[tid];
            #pragma unroll
            for (int d = 1; d < 16; d <<= 1) {
                int t = __shfl_up(w, d, 16);
                if (tid >= d) w += t;
            }
            wscan[tid] = w;
        }
        __syncthreads();
        int woff = (wv == 0) ? 0 : wscan[wv - 1];
        int excl = base + woff + v - orig;
        if (i < NN) { o[i] = excl; cur[i] = excl; }
        base += wscan[15];
    }
    if (tid == 0) o[NN] = base;
}

__global__ __launch_bounds__(256) void scatter_kernel(const int* __restrict__ adj0,
                                                      const int* __restrict__ adj1,
                                                      int* cursor, int* esrc)
{
    int e = blockIdx.x * 256 + threadIdx.x;
    if (e >= 2 * EE) return;
    int b = e / EE, le = e - b * EE;
    const int* adj = b ? adj1 : adj0;
    int src = adj[2 * le + 0];
    int tgt = adj[2 * le + 1];
    int pos = atomicAdd(&cursor[b * NN + tgt], 1);
    esrc[(size_t)b * EE + pos] = src;
}

// ---------------- embedding gather + projection (MFMA), flat h output -------
__global__ __launch_bounds__(256) void projm_kernel(const void* emb,
                                                    const int* __restrict__ i0,
                                                    const int* __restrict__ i1,
                                                    const float* __restrict__ P,
                                                    const u16* __restrict__ PB,
                                                    u16* __restrict__ h, const int* flag)
{
    __shared__ u16 sA[64 * APAD];
    int isbf = *flag;
    int tid = threadIdx.x;
    int node0 = blockIdx.x * 64;

    // stage 64 embedding rows, 4 threads per row (wave w stages+reads rows 16w..16w+15)
    {
        int r = tid >> 2, sub = tid & 3;
        int n = node0 + r;
        int b = n >= NN;
        int ln = n - b * NN;
        int idx = b ? i1[ln] : i0[ln];
        if (isbf) {
            const ushort4* src = (const ushort4*)((const u16*)emb + (size_t)idx * EMBD);
            ushort4* dst = (ushort4*)(sA + r * APAD);
            for (int c = sub; c < 75; c += 4) dst[c] = src[c];
            if (sub == 0) {
                ushort4 z = {0, 0, 0, 0};
                for (int c = 75; c < 80; ++c) dst[c] = z;
            }
        } else {
            const float* src = (const float*)emb + (size_t)idx * EMBD;
            for (int k = sub; k < 300; k += 4) sA[r * APAD + k] = f2b(src[k]);
            if (sub == 0) for (int k = 300; k < 320; ++k) sA[r * APAD + k] = 0;
        }
    }

    int wv = tid >> 6, lane = tid & 63, quad = lane >> 4, cn = lane & 15;
    int m0 = wv * 16;
    f32x4 acc[4];
    #pragma unroll
    for (int j = 0; j < 4; ++j) {
        float bb = P[OFF_PROJB + j * 16 + cn];
        acc[j] = {bb, bb, bb, bb};
    }
    #pragma unroll
    for (int kt = 0; kt < 10; ++kt) {
        s16x8 a = *(const s16x8*)&sA[(m0 + cn) * APAD + kt * 32 + quad * 8];
        #pragma unroll
        for (int j = 0; j < 4; ++j) {
            s16x8 bfr = *(const s16x8*)&PB[PB_PROJT + (j * 10 + kt) * 512 + lane * 8];
            acc[j] = __builtin_amdgcn_mfma_f32_16x16x32_bf16(a, bfr, acc[j], 0, 0, 0);
        }
    }
    #pragma unroll
    for (int j = 0; j < 4; ++j)
        #pragma unroll
        for (int r = 0; r < 4; ++r)
            h[(size_t)(node0 + m0 + quad * 4 + r) * 64 + j * 16 + cn] = f2b(acc[j][r]);
}

// ---------------- fused 6-step propagation (cooperative) ----------------------
// One cooperative kernel runs ALL 6 GGNN steps; grid.sync() is the inter-step
// dependency. 625 blocks x 256 thr, 2 node-tiles (32 nodes) per block per step.
// __launch_bounds__(256,3): 3 blocks/CU co-residency guaranteed (coop launch
// requires all 625 resident; 3x256 CUs = 768 >= 625).
// Phase A: team of 8 lanes per node gathers full 64-feat neighbor rows with
//          dwordx4 loads, accumulates f32, writes S (bf16) + own h row to LDS.
// Phase B: MFMA GRU on the 32x64 tile (4 waves = 2 row x 2 col tiles).
__global__ __launch_bounds__(256, 3) void floop_kernel(u16* __restrict__ h0,
                                                       u16* __restrict__ h1,
                                                       const int* __restrict__ ioff,
                                                       const int* __restrict__ esrc,
                                                       const float* __restrict__ P,
                                                       const u16* __restrict__ PB)
{
    cg::grid_group grid = cg::this_grid();

    __shared__ u16 s_S[32 * 64];
    __shared__ u16 s_h[32 * 64];
    __shared__ float s_deg[32];

    int tid = threadIdx.x;
    int wv = tid >> 6, lane = tid & 63;
    int wr = wv >> 1, wc = wv & 1;
    int m0 = wr * 16;
    int quad = lane >> 4, cn = lane & 15;
    int arow = (m0 + cn) * 64 + quad * 8;
    int fl = lane * 8;

    for (int step = 0; step < 6; ++step) {
        int l = (step >= 3) ? 1 : 0;
        const u16* h_old = (step & 1) ? h1 : h0;
        u16*       h_new = (step & 1) ? h0 : h1;

        for (int tile = 0; tile < 2; ++tile) {
            int node0 = (blockIdx.x * 2 + tile) * 32;

            // ---------------- phase A: gather ----------------
            {
                int team = tid >> 3, oct = tid & 7;
                int node = node0 + team;
                int br = node >= NN;
                int ln = node - br * NN;
                const int* o = ioff + (size_t)br * (NN + 1);
                int s0 = o[ln], s1 = o[ln + 1];
                const int* es = esrc + (size_t)br * EE;
                const u16* hb = h_old + (size_t)br * NN * 64;

                // own row + degree first: overlaps the index-load latency below
                *(uint4*)&s_h[team * 64 + oct * 8] =
                    *(const uint4*)&h_old[(size_t)node * 64 + oct * 8];
                if (oct == 0) s_deg[team] = (float)(s1 - s0);

                float acc[8];
                #pragma unroll
                for (int k = 0; k < 8; ++k) acc[k] = 0.f;

                int base = s0, rem = s1 - s0;
                while (rem > 0) {
                    int cnt = rem < 8 ? rem : 8;
                    int myidx = es[base + (oct < cnt ? oct : cnt - 1)];
                    #pragma unroll
                    for (int j = 0; j < 8; ++j) {
                        int e = __shfl(myidx, j, 8);    // dup of last edge when j>=cnt
                        uint4 v = *(const uint4*)&hb[(size_t)e * 64 + oct * 8];
                        float w = (j < cnt) ? 1.f : 0.f;
                        #pragma unroll
                        for (int p = 0; p < 4; ++p) {
                            unsigned int u = ((const unsigned int*)&v)[p];
                            union { unsigned int i; float f; } lo, hi;
                            lo.i = u << 16; hi.i = u & 0xffff0000u;
                            acc[2 * p]     += w * lo.f;
                            acc[2 * p + 1] += w * hi.f;
                        }
                    }
                    base += cnt;
                    rem -= cnt;
                }

                u16 pk[8];
                #pragma unroll
                for (int k = 0; k < 8; ++k) pk[k] = f2b(acc[k]);
                *(uint4*)&s_S[team * 64 + oct * 8] = *(const uint4*)pk;
            }
            __syncthreads();

            // ---------------- phase B: GRU ----------------
            s16x8 aS0 = *(const s16x8*)&s_S[arow];
            s16x8 aS1 = *(const s16x8*)&s_S[arow + 32];
            s16x8 aH0 = *(const s16x8*)&s_h[arow];
            s16x8 aH1 = *(const s16x8*)&s_h[arow + 32];
            __syncthreads();   // all S-frag reads done before inc overwrites s_S

            // inc = S @ msgW + deg*msgb  (this wave: cols [wc*32, wc*32+32))
            const u16* WM = PB + PB_WMT + (size_t)l * 4096;
            #pragma unroll
            for (int jtl = 0; jtl < 2; ++jtl) {
                int jt = wc * 2 + jtl;
                float mb = P[OFF_MSGB + l * 64 + jt * 16 + cn];
                f32x4 acc;
                acc[0] = s_deg[m0 + quad * 4 + 0] * mb;
                acc[1] = s_deg[m0 + quad * 4 + 1] * mb;
                acc[2] = s_deg[m0 + quad * 4 + 2] * mb;
                acc[3] = s_deg[m0 + quad * 4 + 3] * mb;
                acc = __builtin_amdgcn_mfma_f32_16x16x32_bf16(aS0, *(const s16x8*)&WM[(jt * 2 + 0) * 512 + fl], acc, 0, 0, 0);
                acc = __builtin_amdgcn_mfma_f32_16x16x32_bf16(aS1, *(const s16x8*)&WM[(jt * 2 + 1) * 512 + fl], acc, 0, 0, 0);
                #pragma unroll
                for (int r = 0; r < 4; ++r)
                    s_S[(m0 + quad * 4 + r) * 64 + jt * 16 + cn] = f2b(acc[r]);
            }
            __syncthreads();   // full inc rows ready

            s16x8 aI0 = *(const s16x8*)&s_S[arow];
            s16x8 aI1 = *(const s16x8*)&s_S[arow + 32];
            const u16* WI = PB + PB_WIH + (size_t)l * 12288;
            const u16* WH = PB + PB_WHH + (size_t)l * 12288;
            const float* bi = P + OFF_BIH + l * 192;
            const float* bh = P + OFF_BHH + l * 192;

            #pragma unroll
            for (int cl = 0; cl < 2; ++cl) {
                int jt = wc * 2 + cl;
                int j0 = jt * 16;
                float vr = bi[j0 + cn], vz = bi[64 + j0 + cn], vn = bi[128 + j0 + cn];
                float wr_ = bh[j0 + cn], wz = bh[64 + j0 + cn], wn = bh[128 + j0 + cn];
                f32x4 gr = {vr, vr, vr, vr}, gz = {vz, vz, vz, vz}, gn = {vn, vn, vn, vn};
                f32x4 hr = {wr_, wr_, wr_, wr_}, hz = {wz, wz, wz, wz}, hn = {wn, wn, wn, wn};
                int fr = (jt * 2) * 512 + fl, frz = ((4 + jt) * 2) * 512 + fl, frn = ((8 + jt) * 2) * 512 + fl;
                gr = __builtin_amdgcn_mfma_f32_16x16x32_bf16(aI0, *(const s16x8*)&WI[fr], gr, 0, 0, 0);
                gr = __builtin_amdgcn_mfma_f32_16x16x32_bf16(aI1, *(const s16x8*)&WI[fr + 512], gr, 0, 0, 0);
                gz = __builtin_amdgcn_mfma_f32_16x16x32_bf16(aI0, *(const s16x8*)&WI[frz], gz, 0, 0, 0);
                gz = __builtin_amdgcn_mfma_f32_16x16x32_bf16(aI1, *(const s16x8*)&WI[frz + 512], gz, 0, 0, 0);
                gn = __builtin_amdgcn_mfma_f32_16x16x32_bf16(aI0, *(const s16x8*)&WI[frn], gn, 0, 0, 0);
                gn = __builtin_amdgcn_mfma_f32_16x16x32_bf16(aI1, *(const s16x8*)&WI[frn + 512], gn, 0, 0, 0);
                hr = __builtin_amdgcn_mfma_f32_16x16x32_bf16(aH0, *(const s16x8*)&WH[fr], hr, 0, 0, 0);
                hr = __builtin_amdgcn_mfma_f32_16x16x32_bf16(aH1, *(const s16x8*)&WH[fr + 512], hr, 0, 0, 0);
                hz = __builtin_amdgcn_mfma_f32_16x16x32_bf16(aH0, *(const s16x8*)&WH[frz], hz, 0, 0, 0);
                hz = __builtin_amdgcn_mfma_f32_16x16x32_bf16(aH1, *(const s16x8*)&WH[frz + 512], hz, 0, 0, 0);
                hn = __builtin_amdgcn_mfma_f32_16x16x32_bf16(aH0, *(const s16x8*)&WH[frn], hn, 0, 0, 0);
                hn = __builtin_amdgcn_mfma_f32_16x16x32_bf16(aH1, *(const s16x8*)&WH[frn + 512], hn, 0, 0, 0);
                #pragma unroll
                for (int r = 0; r < 4; ++r) {
                    int row = m0 + quad * 4 + r;
                    float rr = 1.f / (1.f + __expf(-(gr[r] + hr[r])));
                    float zz = 1.f / (1.f + __expf(-(gz[r] + hz[r])));
                    float nn = tanhf(gn[r] + rr * hn[r]);
                    float ho = b2f(s_h[row * 64 + j0 + cn]);
                    h_new[(size_t)(node0 + row) * 64 + j0 + cn] = f2b((1.f - zz) * nn + zz * ho);
                }
            }
            __syncthreads();   // epilogue s_h reads done before next tile's phase A
        }
        grid.sync();           // step t+1 reads what step t wrote (other blocks)
    }
}

// ---------------- classifier: wave-per-sample (flat h reads) ------------------
__global__ __launch_bounds__(256) void cls_kernel(const u16* __restrict__ h,
                                                  const int* __restrict__ p0,
                                                  const int* __restrict__ p1,
                                                  const int* __restrict__ labels,
                                                  const float* __restrict__ P,
                                                  void* out, float* partial, const int* flag)
{
    int isbf = *flag;
    int wv = threadIdx.x >> 6, lane = threadIdx.x & 63;
    int s = blockIdx.x * 4 + wv;               // 1024 blocks x 4 waves = 4096
    int n0 = p0[s], n1 = p1[s];
    float f0 = b2f(h[(size_t)n0 * 64 + lane]);
    float f1 = b2f(h[(size_t)(NN + n1) * 64 + lane]);
    float z = P[OFF_CB2];
    #pragma unroll
    for (int t = 0; t < 16; ++t) {
        float part = f0 * P[OFF_CW1T + t * 128 + lane] + f1 * P[OFF_CW1T + t * 128 + 64 + lane];
        #pragma unroll
        for (int off = 32; off; off >>= 1) part += __shfl_xor(part, off);
        z += fmaxf(part + P[OFF_CB1 + t], 0.f) * P[OFF_CW2 + t];
    }
    float p = 1.f / (1.f + expf(-z));
    float y = (float)labels[s];
    const float eps = 1e-7f;
    float pc  = fminf(fmaxf(p, eps), 1.f);
    float pc1 = fminf(fmaxf(1.f - p, eps), 1.f);
    float term = y * logf(pc) + (1.f - y) * logf(pc1);
    __shared__ float red[4];
    if (lane == 0) { stf(out, s, isbf, p); red[wv] = term; }
    __syncthreads();
    if (threadIdx.x == 0) partial[blockIdx.x] = red[0] + red[1] + red[2] + red[3];
}

__global__ __launch_bounds__(256) void loss_kernel(const float* __restrict__ partial,
                                                   void* out, const int* flag)
{
    __shared__ float red[256];
    int tid = threadIdx.x;
    float s = 0.f;
    for (int i = tid; i < 1024; i += 256) s += partial[i];
    red[tid] = s;
    __syncthreads();
    for (int d = 128; d > 0; d >>= 1) {
        if (tid < d) red[tid] += red[tid + d];
        __syncthreads();
    }
    if (tid == 0) stf(out, BB, *flag, -red[0] / (float)BB);
}

extern "C" void kernel_launch(void* const* d_in, const int* in_sizes, int n_in,
                              void* d_out, int out_size, void* d_ws, size_t ws_size,
                              hipStream_t stream)
{
    const int* adj0   = (const int*)d_in[2];
    const int* adj1   = (const int*)d_in[3];
    const int* prop0  = (const int*)d_in[4];
    const int* prop1  = (const int*)d_in[5];
    const int* labels = (const int*)d_in[6];

    int* flag = (int*)d_ws;
    float* P  = (float*)d_ws + 16;
    u16* PB   = (u16*)(P + PARAM_SZ);
    u16* h0   = PB + PB_SZ;                    // flat: 40000 x 64 bf16
    u16* h1   = h0 + (size_t)NODES * 64;
    float* partial = (float*)(h1 + (size_t)NODES * 64);
    int* ioff   = (int*)(partial + 1024);
    int* cursor = ioff + 2 * (NN + 1) + 62;
    int* esrc   = cursor + 2 * NN;

    hipMemsetAsync(ioff, 0, 2 * (NN + 1) * sizeof(int), stream);

    sniff_kernel<<<1, 64, 0, stream>>>((const u16*)d_in[8], flag);
    conv_kernel<<<96, 256, 0, stream>>>(d_in[8], d_in[9], d_in[10], d_in[11], d_in[12], d_in[13],
                                        d_in[14], d_in[15], d_in[16], d_in[17], d_in[18], d_in[19],
                                        P, PB, flag);
    hist_kernel<<<(2 * EE) / 256, 256, 0, stream>>>(adj0, adj1, ioff);
    scan_kernel<<<2, 1024, 0, stream>>>(ioff, cursor);
    scatter_kernel<<<(2 * EE) / 256, 256, 0, stream>>>(adj0, adj1, cursor, esrc);
    projm_kernel<<<(2 * NN) / 64, 256, 0, stream>>>(d_in[7], (const int*)d_in[0],
                                                    (const int*)d_in[1], P, PB, h0, flag);

    // all 6 GGNN steps in one cooperative kernel; final state lands in h0
    {
        void* args[] = { (void*)&h0, (void*)&h1, (void*)&ioff, (void*)&esrc,
                         (void*)&P, (void*)&PB };
        hipLaunchCooperativeKernel((const void*)floop_kernel, dim3(625), dim3(256),
                                   args, 0, stream);
    }

    cls_kernel<<<BB / 4, 256, 0, stream>>>(h0, prop0, prop1, labels, P, d_out, partial, flag);
    loss_kernel<<<1, 256, 0, stream>>>(partial, d_out, flag);
}

// Round 4
// 392.807 us; speedup vs baseline: 2.8132x; 2.8132x over previous
//
#include <hip/hip_runtime.h>
#include <hip/hip_bf16.h>

typedef unsigned short u16;
typedef __attribute__((ext_vector_type(8))) short s16x8;   // 8 bf16 MFMA A/B frag
typedef __attribute__((ext_vector_type(4))) float f32x4;   // MFMA C/D frag

#define NN 20000
#define HH 64
#define EMBD 300
#define EE 160000
#define BB 4096
#define NODES 40000

// f32 param block offsets (floats) in workspace (after 16-float header)
#define OFF_PROJB 0
#define OFF_MSGB  64
#define OFF_BIH   192
#define OFF_BHH   576
#define OFF_CW1T  960
#define OFF_CB1   3008
#define OFF_CW2   3024
#define OFF_CB2   3040
#define PARAM_SZ  3072

// bf16 frag-swizzled weight blocks (u16 units). Each "frag" = 512 u16 = one
// 16(row)x32(k) B-tile stored so lane L reads its 8 elements at frag*512+L*8.
#define PB_WIH   0        // 2 l x 24 frags (jt 0..11, kt 0..1)
#define PB_WHH   24576
#define PB_WMT   49152    // 2 l x 8 frags (jt 0..3, kt 0..1)
#define PB_PROJT 57344    // 40 frags (frag = jt*10+kt, jt 0..3, kt 0..9)
#define PB_SZ    77824

// projm LDS A-tile row stride (u16): 344 -> 172 dwords, <=2-way bank alias (free)
#define APAD 344

__device__ __forceinline__ float b2f(u16 u) {
    union { unsigned int i; float f; } v; v.i = ((unsigned int)u) << 16; return v.f;
}
__device__ __forceinline__ u16 f2b(float f) {
    union { float f; unsigned int u; } v; v.f = f;
    unsigned int u = v.u;
    return (u16)((u + 0x7FFFu + ((u >> 16) & 1u)) >> 16);   // RNE
}
__device__ __forceinline__ float ldf(const void* p, long long i, int isbf) {
    return isbf ? b2f(((const u16*)p)[i]) : ((const float*)p)[i];
}
__device__ __forceinline__ u16 ldb(const void* p, long long i, int isbf) {
    return isbf ? ((const u16*)p)[i] : f2b(((const float*)p)[i]);
}
__device__ __forceinline__ void stf(void* p, long long i, int isbf, float v) {
    if (isbf) ((u16*)p)[i] = f2b(v);
    else      ((float*)p)[i] = v;
}

// ---------------- dtype sniffer ----------------
__global__ void sniff_kernel(const u16* probe, int* flag)
{
    if (threadIdx.x == 0 && blockIdx.x == 0) {
        int good = 0;
        for (int i = 0; i < 128; i += 2) {
            unsigned int e = (probe[i] >> 7) & 0xFF;
            if (e >= 105 && e <= 127) good++;
        }
        *flag = (good >= 48) ? 1 : 0;
    }
}

// ---------------- param convert + frag swizzle ----------------
__global__ __launch_bounds__(256) void conv_kernel(
    const void* projW, const void* projb, const void* msgW, const void* msgb,
    const void* wih, const void* whh, const void* bih, const void* bhh,
    const void* cw1, const void* cb1, const void* cw2, const void* cb2,
    float* P, u16* PB, const int* flag)
{
    int isbf = *flag;
    int i = blockIdx.x * 256 + threadIdx.x;
    if (i < 64)    P[OFF_PROJB + i] = ldf(projb, i, isbf);
    if (i < 128)   P[OFF_MSGB + i]  = ldf(msgb, i, isbf);
    if (i < 384)   { P[OFF_BIH + i] = ldf(bih, i, isbf); P[OFF_BHH + i] = ldf(bhh, i, isbf); }
    if (i < 2048)  { int t = i >> 7, k = i & 127; P[OFF_CW1T + i] = ldf(cw1, (long long)k * 16 + t, isbf); }
    if (i < 16)    { P[OFF_CB1 + i] = ldf(cb1, i, isbf); P[OFF_CW2 + i] = ldf(cw2, i, isbf); }
    if (i == 0)    P[OFF_CB2] = ldf(cb2, 0, isbf);

    if (i < 24576) {   // Wih/Whh swizzle: per-l 24 frags
        int l = i / 12288, r = i - l * 12288;
        int frag = r >> 9, rr = r & 511, lane = rr >> 3, e = rr & 7;
        int jt = frag >> 1, kt = frag & 1;
        int srow = jt * 16 + (lane & 15);
        int sk = kt * 32 + ((lane >> 4) << 3) + e;
        long long si = (long long)l * 12288 + srow * 64 + sk;
        PB[PB_WIH + i] = ldb(wih, si, isbf);
        PB[PB_WHH + i] = ldb(whh, si, isbf);
    }
    if (i < 8192) {    // msgW^T swizzle
        int l = i >> 12, r = i & 4095;
        int frag = r >> 9, rr = r & 511, lane = rr >> 3, e = rr & 7;
        int jt = frag >> 1, kt = frag & 1;
        int srow = jt * 16 + (lane & 15);
        int sk = kt * 32 + ((lane >> 4) << 3) + e;
        PB[PB_WMT + i] = ldb(msgW, (long long)l * 4096 + sk * 64 + srow, isbf);
    }
    if (i < 20480) {   // projW^T swizzle, k zero-padded >=300
        int frag = i >> 9, rr = i & 511, lane = rr >> 3, e = rr & 7;
        int jt = frag / 10, kt = frag - jt * 10;
        int srow = jt * 16 + (lane & 15);
        int sk = kt * 32 + ((lane >> 4) << 3) + e;
        PB[PB_PROJT + i] = (sk < 300) ? ldb(projW, (long long)sk * 64 + srow, isbf) : (u16)0;
    }
}

// ---------------- CSR build ----------------
__global__ __launch_bounds__(256) void hist_kernel(const int* __restrict__ adj0,
                                                   const int* __restrict__ adj1, int* off)
{
    int e = blockIdx.x * 256 + threadIdx.x;
    if (e >= 2 * EE) return;
    int b = e / EE, le = e - b * EE;
    const int* adj = b ? adj1 : adj0;
    int tgt = adj[2 * le + 1];
    atomicAdd(&off[b * (NN + 1) + tgt + 1], 1);
}

__global__ __launch_bounds__(1024) void scan_kernel(int* off, int* cursor)
{
    int b = blockIdx.x;
    int* o = off + (size_t)b * (NN + 1);
    int* cur = cursor + (size_t)b * NN;
    __shared__ int wsum[16];
    __shared__ int wscan[16];
    int tid = threadIdx.x, wv = tid >> 6, lane = tid & 63;
    int base = 0;
    for (int start = 0; start < NN; start += 1024) {
        int i = start + tid;
        int v = (i < NN) ? o[i + 1] : 0;
        int orig = v;
        #pragma unroll
        for (int d = 1; d < 64; d <<= 1) {
            int t = __shfl_up(v, d);
            if (lane >= d) v += t;
        }
        if (lane == 63) wsum[wv] = v;
        __syncthreads();
        if (tid < 16) {
            int w = wsum[tid];
            #pragma unroll
            for (int d = 1; d < 16; d <<= 1) {
                int t = __shfl_up(w, d, 16);
                if (tid >= d) w += t;
            }
            wscan[tid] = w;
        }
        __syncthreads();
        int woff = (wv == 0) ? 0 : wscan[wv - 1];
        int excl = base + woff + v - orig;
        if (i < NN) { o[i] = excl; cur[i] = excl; }
        base += wscan[15];
    }
    if (tid == 0) o[NN] = base;
}

__global__ __launch_bounds__(256) void scatter_kernel(const int* __restrict__ adj0,
                                                      const int* __restrict__ adj1,
                                                      int* cursor, int* esrc)
{
    int e = blockIdx.x * 256 + threadIdx.x;
    if (e >= 2 * EE) return;
    int b = e / EE, le = e - b * EE;
    const int* adj = b ? adj1 : adj0;
    int src = adj[2 * le + 0];
    int tgt = adj[2 * le + 1];
    int pos = atomicAdd(&cursor[b * NN + tgt], 1);
    esrc[(size_t)b * EE + pos] = src;
}

// ---------------- embedding gather + projection (MFMA), flat h output -------
__global__ __launch_bounds__(256) void projm_kernel(const void* emb,
                                                    const int* __restrict__ i0,
                                                    const int* __restrict__ i1,
                                                    const float* __restrict__ P,
                                                    const u16* __restrict__ PB,
                                                    u16* __restrict__ h, const int* flag)
{
    __shared__ u16 sA[64 * APAD];
    int isbf = *flag;
    int tid = threadIdx.x;
    int node0 = blockIdx.x * 64;

    // stage 64 embedding rows, 4 threads per row (wave w stages+reads rows 16w..16w+15)
    {
        int r = tid >> 2, sub = tid & 3;
        int n = node0 + r;
        int b = n >= NN;
        int ln = n - b * NN;
        int idx = b ? i1[ln] : i0[ln];
        if (isbf) {
            const ushort4* src = (const ushort4*)((const u16*)emb + (size_t)idx * EMBD);
            ushort4* dst = (ushort4*)(sA + r * APAD);
            for (int c = sub; c < 75; c += 4) dst[c] = src[c];
            if (sub == 0) {
                ushort4 z = {0, 0, 0, 0};
                for (int c = 75; c < 80; ++c) dst[c] = z;
            }
        } else {
            const float* src = (const float*)emb + (size_t)idx * EMBD;
            for (int k = sub; k < 300; k += 4) sA[r * APAD + k] = f2b(src[k]);
            if (sub == 0) for (int k = 300; k < 320; ++k) sA[r * APAD + k] = 0;
        }
    }

    int wv = tid >> 6, lane = tid & 63, quad = lane >> 4, cn = lane & 15;
    int m0 = wv * 16;
    f32x4 acc[4];
    #pragma unroll
    for (int j = 0; j < 4; ++j) {
        float bb = P[OFF_PROJB + j * 16 + cn];
        acc[j] = {bb, bb, bb, bb};
    }
    #pragma unroll
    for (int kt = 0; kt < 10; ++kt) {
        s16x8 a = *(const s16x8*)&sA[(m0 + cn) * APAD + kt * 32 + quad * 8];
        #pragma unroll
        for (int j = 0; j < 4; ++j) {
            s16x8 bfr = *(const s16x8*)&PB[PB_PROJT + (j * 10 + kt) * 512 + lane * 8];
            acc[j] = __builtin_amdgcn_mfma_f32_16x16x32_bf16(a, bfr, acc[j], 0, 0, 0);
        }
    }
    #pragma unroll
    for (int j = 0; j < 4; ++j)
        #pragma unroll
        for (int r = 0; r < 4; ++r)
            h[(size_t)(node0 + m0 + quad * 4 + r) * 64 + j * 16 + cn] = f2b(acc[j][r]);
}

// ---------------- fused gather + GRU step --------------------------------------
// One kernel per propagation step (kernel boundary = grid-wide dependency).
// Block = 32 nodes, 256 threads, 1250 blocks (~5/CU: latency hiding for gather).
// Phase A: team of 8 lanes per node gathers full 128-B (64-feat) neighbor rows
//          with dwordx4 loads (h rows are 128-B ALIGNED -> exactly one cache
//          line per row; pre-R4 misalignment fetched 2 lines/row = 2x traffic).
// Phase B: MFMA GRU on the 32x64 tile (4 waves = 2 row x 2 col tiles).
//          Epilogue stages results in LDS, then teams write full 128-B rows
//          (uint4 x 8 lanes) -> no partial-sector RMW write amplification.
__global__ __launch_bounds__(256) void fstep_kernel(const u16* __restrict__ h_old,
                                                    u16* __restrict__ h_new,
                                                    const int* __restrict__ ioff,
                                                    const int* __restrict__ esrc,
                                                    const float* __restrict__ P,
                                                    const u16* __restrict__ PB, int l)
{
    __shared__ u16 s_S[32 * 64];
    __shared__ u16 s_h[32 * 64];
    __shared__ float s_deg[32];

    int tid = threadIdx.x;
    int node0 = blockIdx.x * 32;

    // ---------------- phase A: gather ----------------
    {
        int team = tid >> 3, oct = tid & 7;
        int node = node0 + team;
        int br = node >= NN;
        int ln = node - br * NN;
        const int* o = ioff + (size_t)br * (NN + 1);
        int s0 = o[ln], s1 = o[ln + 1];
        const int* es = esrc + (size_t)br * EE;
        const u16* hb = h_old + (size_t)br * NN * 64;

        // own row + degree first: overlaps the index-load latency below
        *(uint4*)&s_h[team * 64 + oct * 8] =
            *(const uint4*)&h_old[(size_t)node * 64 + oct * 8];
        if (oct == 0) s_deg[team] = (float)(s1 - s0);

        float acc[8];
        #pragma unroll
        for (int k = 0; k < 8; ++k) acc[k] = 0.f;

        int base = s0, rem = s1 - s0;
        while (rem > 0) {
            int cnt = rem < 8 ? rem : 8;
            int myidx = es[base + (oct < cnt ? oct : cnt - 1)];
            #pragma unroll
            for (int j = 0; j < 8; ++j) {
                int e = __shfl(myidx, j, 8);            // dup of last edge when j>=cnt
                uint4 v = *(const uint4*)&hb[(size_t)e * 64 + oct * 8];
                float w = (j < cnt) ? 1.f : 0.f;
                #pragma unroll
                for (int p = 0; p < 4; ++p) {
                    unsigned int u = ((const unsigned int*)&v)[p];
                    union { unsigned int i; float f; } lo, hi;
                    lo.i = u << 16; hi.i = u & 0xffff0000u;
                    acc[2 * p]     += w * lo.f;
                    acc[2 * p + 1] += w * hi.f;
                }
            }
            base += cnt;
            rem -= cnt;
        }

        u16 pk[8];
        #pragma unroll
        for (int k = 0; k < 8; ++k) pk[k] = f2b(acc[k]);
        *(uint4*)&s_S[team * 64 + oct * 8] = *(const uint4*)pk;
    }
    __syncthreads();

    // ---------------- phase B: GRU ----------------
    int wv = tid >> 6, lane = tid & 63;
    int wr = wv >> 1, wc = wv & 1;
    int m0 = wr * 16;
    int quad = lane >> 4, cn = lane & 15;
    int arow = (m0 + cn) * 64 + quad * 8;
    int fl = lane * 8;

    s16x8 aS0 = *(const s16x8*)&s_S[arow];
    s16x8 aS1 = *(const s16x8*)&s_S[arow + 32];
    s16x8 aH0 = *(const s16x8*)&s_h[arow];
    s16x8 aH1 = *(const s16x8*)&s_h[arow + 32];
    __syncthreads();   // all S-frag reads done before inc overwrites s_S

    // phase 1: inc = S @ msgW + deg*msgb  (this wave: cols [wc*32, wc*32+32))
    const u16* WM = PB + PB_WMT + (size_t)l * 4096;
    #pragma unroll
    for (int jtl = 0; jtl < 2; ++jtl) {
        int jt = wc * 2 + jtl;
        float mb = P[OFF_MSGB + l * 64 + jt * 16 + cn];
        f32x4 acc;
        acc[0] = s_deg[m0 + quad * 4 + 0] * mb;
        acc[1] = s_deg[m0 + quad * 4 + 1] * mb;
        acc[2] = s_deg[m0 + quad * 4 + 2] * mb;
        acc[3] = s_deg[m0 + quad * 4 + 3] * mb;
        acc = __builtin_amdgcn_mfma_f32_16x16x32_bf16(aS0, *(const s16x8*)&WM[(jt * 2 + 0) * 512 + fl], acc, 0, 0, 0);
        acc = __builtin_amdgcn_mfma_f32_16x16x32_bf16(aS1, *(const s16x8*)&WM[(jt * 2 + 1) * 512 + fl], acc, 0, 0, 0);
        #pragma unroll
        for (int r = 0; r < 4; ++r)
            s_S[(m0 + quad * 4 + r) * 64 + jt * 16 + cn] = f2b(acc[r]);
    }
    __syncthreads();   // full inc rows ready

    s16x8 aI0 = *(const s16x8*)&s_S[arow];
    s16x8 aI1 = *(const s16x8*)&s_S[arow + 32];
    __syncthreads();   // aI frag reads done before epilogue re-writes s_S

    const u16* WI = PB + PB_WIH + (size_t)l * 12288;
    const u16* WH = PB + PB_WHH + (size_t)l * 12288;
    const float* bi = P + OFF_BIH + l * 192;
    const float* bh = P + OFF_BHH + l * 192;

    #pragma unroll
    for (int cl = 0; cl < 2; ++cl) {
        int jt = wc * 2 + cl;
        int j0 = jt * 16;
        float vr = bi[j0 + cn], vz = bi[64 + j0 + cn], vn = bi[128 + j0 + cn];
        float wr_ = bh[j0 + cn], wz = bh[64 + j0 + cn], wn = bh[128 + j0 + cn];
        f32x4 gr = {vr, vr, vr, vr}, gz = {vz, vz, vz, vz}, gn = {vn, vn, vn, vn};
        f32x4 hr = {wr_, wr_, wr_, wr_}, hz = {wz, wz, wz, wz}, hn = {wn, wn, wn, wn};
        int fr = (jt * 2) * 512 + fl, frz = ((4 + jt) * 2) * 512 + fl, frn = ((8 + jt) * 2) * 512 + fl;
        gr = __builtin_amdgcn_mfma_f32_16x16x32_bf16(aI0, *(const s16x8*)&WI[fr], gr, 0, 0, 0);
        gr = __builtin_amdgcn_mfma_f32_16x16x32_bf16(aI1, *(const s16x8*)&WI[fr + 512], gr, 0, 0, 0);
        gz = __builtin_amdgcn_mfma_f32_16x16x32_bf16(aI0, *(const s16x8*)&WI[frz], gz, 0, 0, 0);
        gz = __builtin_amdgcn_mfma_f32_16x16x32_bf16(aI1, *(const s16x8*)&WI[frz + 512], gz, 0, 0, 0);
        gn = __builtin_amdgcn_mfma_f32_16x16x32_bf16(aI0, *(const s16x8*)&WI[frn], gn, 0, 0, 0);
        gn = __builtin_amdgcn_mfma_f32_16x16x32_bf16(aI1, *(const s16x8*)&WI[frn + 512], gn, 0, 0, 0);
        hr = __builtin_amdgcn_mfma_f32_16x16x32_bf16(aH0, *(const s16x8*)&WH[fr], hr, 0, 0, 0);
        hr = __builtin_amdgcn_mfma_f32_16x16x32_bf16(aH1, *(const s16x8*)&WH[fr + 512], hr, 0, 0, 0);
        hz = __builtin_amdgcn_mfma_f32_16x16x32_bf16(aH0, *(const s16x8*)&WH[frz], hz, 0, 0, 0);
        hz = __builtin_amdgcn_mfma_f32_16x16x32_bf16(aH1, *(const s16x8*)&WH[frz + 512], hz, 0, 0, 0);
        hn = __builtin_amdgcn_mfma_f32_16x16x32_bf16(aH0, *(const s16x8*)&WH[frn], hn, 0, 0, 0);
        hn = __builtin_amdgcn_mfma_f32_16x16x32_bf16(aH1, *(const s16x8*)&WH[frn + 512], hn, 0, 0, 0);
        #pragma unroll
        for (int r = 0; r < 4; ++r) {
            int row = m0 + quad * 4 + r;
            float rr = 1.f / (1.f + __expf(-(gr[r] + hr[r])));
            float zz = 1.f / (1.f + __expf(-(gz[r] + hz[r])));
            float nn = tanhf(gn[r] + rr * hn[r]);
            float ho = b2f(s_h[row * 64 + j0 + cn]);
            s_S[row * 64 + j0 + cn] = f2b((1.f - zz) * nn + zz * ho);
        }
    }
    __syncthreads();   // all result tiles staged in s_S

    // vectorized epilogue: full 128-B row stores (8 lanes x 16 B per node row)
    {
        int team = tid >> 3, oct = tid & 7;
        int node = node0 + team;
        *(uint4*)&h_new[(size_t)node * 64 + oct * 8] =
            *(const uint4*)&s_S[team * 64 + oct * 8];
    }
}

// ---------------- classifier: wave-per-sample (flat h reads) ------------------
__global__ __launch_bounds__(256) void cls_kernel(const u16* __restrict__ h,
                                                  const int* __restrict__ p0,
                                                  const int* __restrict__ p1,
                                                  const int* __restrict__ labels,
                                                  const float* __restrict__ P,
                                                  void* out, float* partial, const int* flag)
{
    int isbf = *flag;
    int wv = threadIdx.x >> 6, lane = threadIdx.x & 63;
    int s = blockIdx.x * 4 + wv;               // 1024 blocks x 4 waves = 4096
    int n0 = p0[s], n1 = p1[s];
    float f0 = b2f(h[(size_t)n0 * 64 + lane]);
    float f1 = b2f(h[(size_t)(NN + n1) * 64 + lane]);
    float z = P[OFF_CB2];
    #pragma unroll
    for (int t = 0; t < 16; ++t) {
        float part = f0 * P[OFF_CW1T + t * 128 + lane] + f1 * P[OFF_CW1T + t * 128 + 64 + lane];
        #pragma unroll
        for (int off = 32; off; off >>= 1) part += __shfl_xor(part, off);
        z += fmaxf(part + P[OFF_CB1 + t], 0.f) * P[OFF_CW2 + t];
    }
    float p = 1.f / (1.f + expf(-z));
    float y = (float)labels[s];
    const float eps = 1e-7f;
    float pc  = fminf(fmaxf(p, eps), 1.f);
    float pc1 = fminf(fmaxf(1.f - p, eps), 1.f);
    float term = y * logf(pc) + (1.f - y) * logf(pc1);
    __shared__ float red[4];
    if (lane == 0) { stf(out, s, isbf, p); red[wv] = term; }
    __syncthreads();
    if (threadIdx.x == 0) partial[blockIdx.x] = red[0] + red[1] + red[2] + red[3];
}

__global__ __launch_bounds__(256) void loss_kernel(const float* __restrict__ partial,
                                                   void* out, const int* flag)
{
    __shared__ float red[256];
    int tid = threadIdx.x;
    float s = 0.f;
    for (int i = tid; i < 1024; i += 256) s += partial[i];
    red[tid] = s;
    __syncthreads();
    for (int d = 128; d > 0; d >>= 1) {
        if (tid < d) red[tid] += red[tid + d];
        __syncthreads();
    }
    if (tid == 0) stf(out, BB, *flag, -red[0] / (float)BB);
}

extern "C" void kernel_launch(void* const* d_in, const int* in_sizes, int n_in,
                              void* d_out, int out_size, void* d_ws, size_t ws_size,
                              hipStream_t stream)
{
    const int* adj0   = (const int*)d_in[2];
    const int* adj1   = (const int*)d_in[3];
    const int* prop0  = (const int*)d_in[4];
    const int* prop1  = (const int*)d_in[5];
    const int* labels = (const int*)d_in[6];

    int* flag = (int*)d_ws;
    float* P  = (float*)d_ws + 16;
    u16* PB   = (u16*)(P + PARAM_SZ);
    // h rows are 128 B; align h0 to 256 B so every row is exactly one cache
    // line (misaligned rows straddle 2 lines -> 2x gather fetch traffic).
    u16* h0   = (u16*)(((uintptr_t)(PB + PB_SZ) + 255) & ~(uintptr_t)255);
    u16* h1   = h0 + (size_t)NODES * 64;
    float* partial = (float*)(h1 + (size_t)NODES * 64);
    int* ioff   = (int*)(partial + 1024);
    int* cursor = ioff + 2 * (NN + 1) + 62;
    int* esrc   = cursor + 2 * NN;

    hipMemsetAsync(ioff, 0, 2 * (NN + 1) * sizeof(int), stream);

    sniff_kernel<<<1, 64, 0, stream>>>((const u16*)d_in[8], flag);
    conv_kernel<<<96, 256, 0, stream>>>(d_in[8], d_in[9], d_in[10], d_in[11], d_in[12], d_in[13],
                                        d_in[14], d_in[15], d_in[16], d_in[17], d_in[18], d_in[19],
                                        P, PB, flag);
    hist_kernel<<<(2 * EE) / 256, 256, 0, stream>>>(adj0, adj1, ioff);
    scan_kernel<<<2, 1024, 0, stream>>>(ioff, cursor);
    scatter_kernel<<<(2 * EE) / 256, 256, 0, stream>>>(adj0, adj1, cursor, esrc);
    projm_kernel<<<(2 * NN) / 64, 256, 0, stream>>>(d_in[7], (const int*)d_in[0],
                                                    (const int*)d_in[1], P, PB, h0, flag);

    u16* hcur = h0;
    u16* hnext = h1;
    for (int l = 0; l < 2; ++l) {
        for (int t = 0; t < 3; ++t) {
            fstep_kernel<<<NODES / 32, 256, 0, stream>>>(hcur, hnext, ioff, esrc, P, PB, l);
            u16* tmp = hcur; hcur = hnext; hnext = tmp;
        }
    }
    // 6 steps -> final state back in h0 (== hcur)

    cls_kernel<<<BB / 4, 256, 0, stream>>>(hcur, prop0, prop1, labels, P, d_out, partial, flag);
    loss_kernel<<<1, 256, 0, stream>>>(partial, d_out, flag);
}